// Round 7
// baseline (279.283 us; speedup 1.0000x reference)
//
#include <hip/hip_runtime.h>
#include <hip/hip_bf16.h>
#include <math.h>

// Problem constants
#define Bc  32
#define Nn  512
#define Dd  256
#define Hh  8
#define HDd 32
#define Ee  16384
#define KT  128   // attention k-tile

typedef __attribute__((ext_vector_type(8))) short bf16x8;
typedef __attribute__((ext_vector_type(4))) float f32x4;

__device__ inline ushort f2bf(float x){
  union { float f; unsigned u; } v; v.f = x;
  return (ushort)((v.u + 0x7fff + ((v.u >> 16) & 1)) >> 16);   // RNE
}

// ---------------- graph prep: dense normalized adjacency ----------------

__global__ __launch_bounds__(256) void k_count(const int* __restrict__ ei, int* __restrict__ count){
  int e = blockIdx.x*256 + threadIdx.x;
  if (e < Ee) atomicAdd(&count[ei[Ee + e]], 1);
}

__global__ __launch_bounds__(256) void k_scatter(const int* __restrict__ ei, const int* __restrict__ count,
                                                 float* __restrict__ S){
  int e = blockIdx.x*256 + threadIdx.x;
  if (e < Ee){
    int s = ei[e], d = ei[Ee + e];
    float w = rsqrtf((1.0f + (float)count[s]) * (1.0f + (float)count[d]));
    atomicAdd(&S[d*Nn + s], w);   // duplicates accumulate, matches ref
  }
}

// add self-loop diagonal, convert to bf16
__global__ __launch_bounds__(256) void k_sbf(const float* __restrict__ S, const int* __restrict__ count,
                                             ushort* __restrict__ Sb){
  int base = (blockIdx.x*256 + threadIdx.x)*4;
  #pragma unroll
  for (int j = 0; j < 4; j++){
    int i = base + j;
    int d = i >> 9, s = i & (Nn-1);
    float v = S[i] + ((d == s) ? 1.0f/(1.0f + (float)count[d]) : 0.0f);
    Sb[i] = f2bf(v);
  }
}

// ---------------- W transpose+convert (z<4) + mask bit-pack (z==4) ----------------
__global__ __launch_bounds__(256) void k_wt(const float* __restrict__ Wq, const float* __restrict__ Wk,
                                            const float* __restrict__ Wv, const float* __restrict__ Wo,
                                            const int* __restrict__ mask,
                                            ushort* __restrict__ Wtq, ushort* __restrict__ Wtk,
                                            ushort* __restrict__ Wtv, ushort* __restrict__ Wto,
                                            ushort* __restrict__ Mbits){
  __shared__ float Ls[64][65];
  int mat = blockIdx.z;
  if (mat == 4){
    int bid = blockIdx.y*4 + blockIdx.x;        // 0..15
    int w0 = bid*1024 + threadIdx.x*4;
    #pragma unroll
    for (int j = 0; j < 4; j++){
      int w = w0 + j;
      int row = w >> 5, c0 = (w & 31) << 4;
      unsigned bits = 0;
      #pragma unroll
      for (int i = 0; i < 16; i++)
        bits |= (mask[(size_t)row*Nn + c0 + i] != 0 ? 1u : 0u) << i;
      Mbits[w] = (ushort)bits;
    }
    return;
  }
  const float* Wsrc = (mat==0)?Wq:(mat==1)?Wk:(mat==2)?Wv:Wo;
  ushort* Wt = (mat==0)?Wtq:(mat==1)?Wtk:(mat==2)?Wtv:Wto;
  int k0 = blockIdx.x*64, n0 = blockIdx.y*64;
  int t = threadIdx.x;
  {
    int r = t >> 2, c4 = (t & 3)*16;
    #pragma unroll
    for (int j = 0; j < 16; j += 4)
      *(float4*)&Ls[r][c4+j] = *(const float4*)(Wsrc + (size_t)(k0+r)*Dd + n0 + c4 + j);
  }
  __syncthreads();
  int nr = t >> 2, kc = (t & 3)*16;
  ushort hb[16];
  #pragma unroll
  for (int j = 0; j < 16; j++) hb[j] = f2bf(Ls[kc+j][nr]);
  size_t dst = (size_t)(n0+nr)*Dd + k0 + kc;
  *(int4*)(Wt + dst)     = ((int4*)hb)[0];
  *(int4*)(Wt + dst + 8) = ((int4*)hb)[1];
}

// ============ shared GEMM pipeline helpers (128x64 tile, K-chunk 64) ============
// LDS: unpadded, XOR-swizzled: element chunk c8 (8 ushorts) of row r stored at
// slot c8^(r&7). Staging ds_write_b128 is linear (lane i -> byte i*16, 2-way=free);
// frag ds_read_b128 spans all 8 chunk slots across 8 rows (2-way=free).
// Pipeline: [ds_write tile k][prefetch k+1 -> regs][barrier][compute k] — one
// barrier/iter; vmcnt wait for prefetch lands after the MFMA phase.

#define GEMM_COMPUTE(Ap, Bp)                                                     \
  _Pragma("unroll")                                                              \
  for (int kk = 0; kk < 2; kk++){                                                \
    bf16x8 af[2];                                                                \
    _Pragma("unroll")                                                            \
    for (int r2 = 0; r2 < 2; r2++){                                              \
      int ra_ = wave*32 + r2*16 + l16;                                           \
      af[r2] = *(const bf16x8*)((Ap) + ra_*64 + (((kk<<2)+g) ^ (ra_&7))*8);      \
    }                                                                            \
    _Pragma("unroll")                                                            \
    for (int nf = 0; nf < 4; nf++){                                              \
      int rb_ = nf*16 + l16;                                                     \
      bf16x8 bfr = *(const bf16x8*)((Bp) + rb_*64 + (((kk<<2)+g) ^ (rb_&7))*8);  \
      _Pragma("unroll")                                                          \
      for (int r2 = 0; r2 < 2; r2++)                                             \
        acc[r2][nf] = __builtin_amdgcn_mfma_f32_16x16x32_bf16(af[r2], bfr, acc[r2][nf], 0, 0, 0); \
    }                                                                            \
  }

// ---------------- k_proj: T = X@W (no bias), output transposed Tt[b][ch][node] bf16
__global__ __launch_bounds__(256) void k_proj(const float* __restrict__ q, const float* __restrict__ k,
                                              const float* __restrict__ v,
                                              const ushort* __restrict__ Wtq, const ushort* __restrict__ Wtk,
                                              const ushort* __restrict__ Wtv,
                                              ushort* __restrict__ Ttq, ushort* __restrict__ Ttk,
                                              ushort* __restrict__ Ttv){
  int z = blockIdx.z;
  int which = z >> 5, b = z & 31;
  const float*  X  = (which==0)?q:(which==1)?k:v;
  const ushort* Wt = (which==0)?Wtq:(which==1)?Wtk:Wtv;
  ushort*       Tt = (which==0)?Ttq:(which==1)?Ttk:Ttv;

  __shared__ ushort AsL[2][128*64];
  __shared__ ushort BsL[2][64*64];

  int t = threadIdx.x, wave = t >> 6, lane = t & 63;
  int g = lane >> 4, l16 = lane & 15;
  int m0 = blockIdx.x*128, n0 = blockIdx.y*64;

  f32x4 acc[2][4] = {};
  float4 rx[8]; int4 rb[2];

  // prefetch tile 0
  #pragma unroll
  for (int i = 0; i < 4; i++){
    int id = t + i*256, row = id >> 3, c8 = (id & 7) ^ (row & 7);
    const float* src = X + ((size_t)b*Nn + m0 + row)*Dd + 0 + c8*8;
    rx[2*i]   = *(const float4*)(src);
    rx[2*i+1] = *(const float4*)(src + 4);
  }
  #pragma unroll
  for (int i = 0; i < 2; i++){
    int id = t + i*256, row = id >> 3, c8 = (id & 7) ^ (row & 7);
    rb[i] = *(const int4*)(Wt + (size_t)(n0 + row)*Dd + 0 + c8*8);
  }

  for (int kt = 0; kt < 4; kt++){
    ushort* Ap = &AsL[kt & 1][0];
    ushort* Bp = &BsL[kt & 1][0];
    // regs -> LDS (linear swizzled)
    #pragma unroll
    for (int i = 0; i < 4; i++){
      int id = t + i*256;
      ushort ta[8];
      #pragma unroll
      for (int j = 0; j < 4; j++) ta[j]   = f2bf(((const float*)&rx[2*i])[j]);
      #pragma unroll
      for (int j = 0; j < 4; j++) ta[4+j] = f2bf(((const float*)&rx[2*i+1])[j]);
      *(int4*)(Ap + id*8) = *(int4*)ta;
    }
    #pragma unroll
    for (int i = 0; i < 2; i++){ int id = t + i*256; *(int4*)(Bp + id*8) = rb[i]; }
    // prefetch next tile
    if (kt < 3){
      int k0 = (kt+1)*64;
      #pragma unroll
      for (int i = 0; i < 4; i++){
        int id = t + i*256, row = id >> 3, c8 = (id & 7) ^ (row & 7);
        const float* src = X + ((size_t)b*Nn + m0 + row)*Dd + k0 + c8*8;
        rx[2*i]   = *(const float4*)(src);
        rx[2*i+1] = *(const float4*)(src + 4);
      }
      #pragma unroll
      for (int i = 0; i < 2; i++){
        int id = t + i*256, row = id >> 3, c8 = (id & 7) ^ (row & 7);
        rb[i] = *(const int4*)(Wt + (size_t)(n0 + row)*Dd + k0 + c8*8);
      }
    }
    __syncthreads();
    GEMM_COMPUTE(Ap, Bp)
  }
  __syncthreads();

  // transposed epilogue via LDS (alias AsL): Ts[n_local][m_local], 64 x 128 (stride 136)
  ushort (*Ts)[136] = (ushort (*)[136])(void*)&AsL[0][0];
  #pragma unroll
  for (int nf = 0; nf < 4; nf++)
    #pragma unroll
    for (int r2 = 0; r2 < 2; r2++)
      #pragma unroll
      for (int rr = 0; rr < 4; rr++)
        Ts[nf*16 + l16][wave*32 + r2*16 + g*4 + rr] = f2bf(acc[r2][nf][rr]);
  __syncthreads();
  #pragma unroll
  for (int i = 0; i < 4; i++){
    int id = t + i*256;
    int nr = id >> 4, mc = (id & 15)*8;
    *(int4*)(Tt + ((size_t)b*Dd + n0 + nr)*Nn + m0 + mc) = *(int4*)&Ts[nr][mc];
  }
}

// ---------------- k_agge: QKV = S @ T + bias
// Q -> head layout pre-scaled; K -> head layout; V -> transposed Vt[b][ch][node]
__global__ __launch_bounds__(256) void k_agge(const ushort* __restrict__ Sb,
                                              const ushort* __restrict__ Ttq, const ushort* __restrict__ Ttk,
                                              const ushort* __restrict__ Ttv,
                                              const float* __restrict__ bq, const float* __restrict__ bk,
                                              const float* __restrict__ bv,
                                              ushort* __restrict__ Qh, ushort* __restrict__ Kh,
                                              ushort* __restrict__ Vt){
  int z = blockIdx.z;
  int which = z >> 5, b = z & 31;
  const ushort* Tt  = (which==0)?Ttq:(which==1)?Ttk:Ttv;
  const float*  bia = (which==0)?bq:(which==1)?bk:bv;

  __shared__ ushort AsL[2][128*64];
  __shared__ ushort BsL[2][64*64];

  int t = threadIdx.x, wave = t >> 6, lane = t & 63;
  int g = lane >> 4, l16 = lane & 15;
  int m0 = blockIdx.x*128, n0 = blockIdx.y*64;

  f32x4 acc[2][4] = {};
  int4 ra[4], rb[2];

  #pragma unroll
  for (int i = 0; i < 4; i++){
    int id = t + i*256, row = id >> 3, c8 = (id & 7) ^ (row & 7);
    ra[i] = *(const int4*)(Sb + (size_t)(m0 + row)*Nn + 0 + c8*8);
  }
  #pragma unroll
  for (int i = 0; i < 2; i++){
    int id = t + i*256, row = id >> 3, c8 = (id & 7) ^ (row & 7);
    rb[i] = *(const int4*)(Tt + ((size_t)b*Dd + n0 + row)*Nn + 0 + c8*8);
  }

  for (int kt = 0; kt < 8; kt++){
    ushort* Ap = &AsL[kt & 1][0];
    ushort* Bp = &BsL[kt & 1][0];
    #pragma unroll
    for (int i = 0; i < 4; i++){ int id = t + i*256; *(int4*)(Ap + id*8) = ra[i]; }
    #pragma unroll
    for (int i = 0; i < 2; i++){ int id = t + i*256; *(int4*)(Bp + id*8) = rb[i]; }
    if (kt < 7){
      int k0 = (kt+1)*64;
      #pragma unroll
      for (int i = 0; i < 4; i++){
        int id = t + i*256, row = id >> 3, c8 = (id & 7) ^ (row & 7);
        ra[i] = *(const int4*)(Sb + (size_t)(m0 + row)*Nn + k0 + c8*8);
      }
      #pragma unroll
      for (int i = 0; i < 2; i++){
        int id = t + i*256, row = id >> 3, c8 = (id & 7) ^ (row & 7);
        rb[i] = *(const int4*)(Tt + ((size_t)b*Dd + n0 + row)*Nn + k0 + c8*8);
      }
    }
    __syncthreads();
    GEMM_COMPUTE(Ap, Bp)
  }
  __syncthreads();

  const float qscale = 0.17677669529663687f * 1.4426950408889634f;  // 1/sqrt(32)*log2(e)

  if (which == 2){
    // V: bias then LDS-transpose -> Vt[(b*256 + channel)][node]
    ushort (*Ts)[136] = (ushort (*)[136])(void*)&AsL[0][0];
    #pragma unroll
    for (int nf = 0; nf < 4; nf++)
      #pragma unroll
      for (int r2 = 0; r2 < 2; r2++)
        #pragma unroll
        for (int rr = 0; rr < 4; rr++){
          int n = n0 + nf*16 + l16;
          Ts[nf*16 + l16][wave*32 + r2*16 + g*4 + rr] = f2bf(acc[r2][nf][rr] + bia[n]);
        }
    __syncthreads();
    #pragma unroll
    for (int i = 0; i < 4; i++){
      int id = t + i*256;
      int nr = id >> 4, mc = (id & 15)*8;
      *(int4*)(Vt + ((size_t)b*Dd + n0 + nr)*Nn + m0 + mc) = *(int4*)&Ts[nr][mc];
    }
  } else {
    ushort* out = (which==0) ? Qh : Kh;
    float sc = (which==0) ? qscale : 1.0f;
    #pragma unroll
    for (int nf = 0; nf < 4; nf++){
      #pragma unroll
      for (int r2 = 0; r2 < 2; r2++)
        #pragma unroll
        for (int rr = 0; rr < 4; rr++){
          int m = m0 + wave*32 + r2*16 + g*4 + rr;   // node
          int n = n0 + nf*16 + l16;                  // out channel
          float val = (acc[r2][nf][rr] + bia[n]) * sc;
          int h = n >> 5, hd = n & 31;
          out[((size_t)(b*Hh + h)*Nn + m)*HDd + hd] = f2bf(val);
        }
    }
  }
}

// ---------------- MFMA attention ----------------
__global__ __launch_bounds__(256) void k_attn(const ushort* __restrict__ Qg, const ushort* __restrict__ Kg,
                                              const ushort* __restrict__ Vt, const ushort* __restrict__ Mbits,
                                              ushort* __restrict__ xh){
  __shared__ ushort Ks[KT][40];        // K rows [k][hd]
  __shared__ ushort Vs[HDd][KT+8];     // V^T [hd][k]
  __shared__ ushort Ps[4][16][KT+8];   // per-wave P bf16

  int bx = blockIdx.x;
  int bh = bx & 255;
  int qt = bx >> 8;
  int b = bh >> 3, h = bh & 7;
  int t = threadIdx.x, wave = t >> 6, lane = t & 63;
  int g = lane >> 4, l16 = lane & 15;

  const ushort* Qp = Qg + (size_t)bh*Nn*HDd;
  const ushort* Kp = Kg + (size_t)bh*Nn*HDd;
  const ushort* Vp = Vt + (size_t)bh*HDd*Nn;

  int q0 = qt*64 + wave*16;
  bf16x8 qfrag = *(const bf16x8*)(Qp + (size_t)(q0 + l16)*HDd + g*8);

  bf16x8 ones;
  #pragma unroll
  for (int j = 0; j < 8; j++) ones[j] = (short)0x3F80;   // 1.0 bf16

  f32x4 Ofrag[2] = {{0,0,0,0},{0,0,0,0}};
  f32x4 rs = {0,0,0,0};

  for (int kt = 0; kt < Nn; kt += KT){
    #pragma unroll
    for (int i = 0; i < 2; i++){
      int id = t + i*256;
      int r = id >> 2, c = (id & 3)*8;
      *(int4*)&Ks[r][c] = *(const int4*)(Kp + (size_t)(kt + r)*HDd + c);
    }
    #pragma unroll
    for (int i = 0; i < 2; i++){
      int id = t + i*256;
      int r = id >> 4, c = (id & 15)*8;
      *(int4*)&Vs[r][c] = *(const int4*)(Vp + (size_t)r*Nn + kt + c);
    }
    __syncthreads();

    int4 mb4[4];
    #pragma unroll
    for (int r = 0; r < 4; r++)
      mb4[r] = *(const int4*)(Mbits + (size_t)(q0 + g*4 + r)*32 + (kt >> 4));

    #pragma unroll
    for (int f = 0; f < KT/16; f++){
      bf16x8 kfrag = *(const bf16x8*)&Ks[f*16 + l16][g*8];
      f32x4 ci;
      #pragma unroll
      for (int r = 0; r < 4; r++){
        unsigned w = ((const unsigned*)&mb4[r])[f >> 1];
        unsigned bit = (w >> ((f & 1)*16 + l16)) & 1u;
        ci[r] = bit ? 0.0f : -1e30f;
      }
      f32x4 s = __builtin_amdgcn_mfma_f32_16x16x32_bf16(qfrag, kfrag, ci, 0, 0, 0);
      #pragma unroll
      for (int r = 0; r < 4; r++){
        float e = __builtin_exp2f(s[r]);            // masked -> 0
        union { float f; unsigned u; } cv; cv.f = e;
        Ps[wave][g*4 + r][f*16 + l16] = (ushort)((cv.u + 0x8000u) >> 16);
      }
    }
    // no barrier: Ps is wave-private, lgkmcnt orders RAW

    #pragma unroll
    for (int ks = 0; ks < KT/32; ks++){
      bf16x8 af = *(const bf16x8*)&Ps[wave][l16][ks*32 + g*8];
      rs = __builtin_amdgcn_mfma_f32_16x16x32_bf16(af, ones, rs, 0, 0, 0);  // row sums
      #pragma unroll
      for (int nt = 0; nt < 2; nt++){
        bf16x8 vf = *(const bf16x8*)&Vs[nt*16 + l16][ks*32 + g*8];
        Ofrag[nt] = __builtin_amdgcn_mfma_f32_16x16x32_bf16(af, vf, Ofrag[nt], 0, 0, 0);
      }
    }
    __syncthreads();
  }

  float inv[4];
  #pragma unroll
  for (int r = 0; r < 4; r++) inv[r] = 1.0f / rs[r];

  #pragma unroll
  for (int nt = 0; nt < 2; nt++){
    #pragma unroll
    for (int r = 0; r < 4; r++){
      int row = q0 + g*4 + r;
      int col = h*HDd + nt*16 + l16;
      xh[((size_t)b*Nn + row)*Dd + col] = f2bf(Ofrag[nt][r] * inv[r]);
    }
  }
}

// ---------------- out-projection: C = x@Wo + bo, pipelined bf16 MFMA
__global__ __launch_bounds__(256) void k_gemm_o(const ushort* __restrict__ xh,
                                                const ushort* __restrict__ Wto,
                                                const float* __restrict__ bo, float* __restrict__ out){
  __shared__ ushort AsL[2][128*64];
  __shared__ ushort BsL[2][64*64];

  int t = threadIdx.x, wave = t >> 6, lane = t & 63;
  int g = lane >> 4, l16 = lane & 15;
  int m0 = blockIdx.x*128, n0 = blockIdx.y*64;

  f32x4 acc[2][4] = {};
  int4 ra[4], rb[2];

  #pragma unroll
  for (int i = 0; i < 4; i++){
    int id = t + i*256, row = id >> 3, c8 = (id & 7) ^ (row & 7);
    ra[i] = *(const int4*)(xh + (size_t)(m0 + row)*Dd + 0 + c8*8);
  }
  #pragma unroll
  for (int i = 0; i < 2; i++){
    int id = t + i*256, row = id >> 3, c8 = (id & 7) ^ (row & 7);
    rb[i] = *(const int4*)(Wto + (size_t)(n0 + row)*Dd + 0 + c8*8);
  }

  for (int kt = 0; kt < 4; kt++){
    ushort* Ap = &AsL[kt & 1][0];
    ushort* Bp = &BsL[kt & 1][0];
    #pragma unroll
    for (int i = 0; i < 4; i++){ int id = t + i*256; *(int4*)(Ap + id*8) = ra[i]; }
    #pragma unroll
    for (int i = 0; i < 2; i++){ int id = t + i*256; *(int4*)(Bp + id*8) = rb[i]; }
    if (kt < 3){
      int k0 = (kt+1)*64;
      #pragma unroll
      for (int i = 0; i < 4; i++){
        int id = t + i*256, row = id >> 3, c8 = (id & 7) ^ (row & 7);
        ra[i] = *(const int4*)(xh + (size_t)(m0 + row)*Dd + k0 + c8*8);
      }
      #pragma unroll
      for (int i = 0; i < 2; i++){
        int id = t + i*256, row = id >> 3, c8 = (id & 7) ^ (row & 7);
        rb[i] = *(const int4*)(Wto + (size_t)(n0 + row)*Dd + k0 + c8*8);
      }
    }
    __syncthreads();
    GEMM_COMPUTE(Ap, Bp)
  }

  #pragma unroll
  for (int nf = 0; nf < 4; nf++){
    #pragma unroll
    for (int r2 = 0; r2 < 2; r2++)
      #pragma unroll
      for (int rr = 0; rr < 4; rr++){
        int m = m0 + wave*32 + r2*16 + g*4 + rr;
        int n = n0 + nf*16 + l16;
        out[(size_t)m*Dd + n] = acc[r2][nf][rr] + bo[n];
      }
  }
}

// ---------------- launch ----------------
extern "C" void kernel_launch(void* const* d_in, const int* in_sizes, int n_in,
                              void* d_out, int out_size, void* d_ws, size_t ws_size,
                              hipStream_t stream){
  const float* query = (const float*)d_in[0];
  const float* key   = (const float*)d_in[1];
  const float* value = (const float*)d_in[2];
  const int*   ei    = (const int*)  d_in[3];
  const int*   mask  = (const int*)  d_in[4];
  const float* Wq = (const float*)d_in[5];
  const float* bq = (const float*)d_in[6];
  const float* Wk = (const float*)d_in[7];
  const float* bk = (const float*)d_in[8];
  const float* Wv = (const float*)d_in[9];
  const float* bv = (const float*)d_in[10];
  const float* Wo = (const float*)d_in[11];
  const float* bo = (const float*)d_in[12];

  char* ws = (char*)d_ws;
  size_t off = 0;
  auto alloc = [&](size_t bytes)->void*{
    void* p = ws + off;
    off = (off + bytes + 255) & ~(size_t)255;
    return p;
  };
  int*    count  = (int*)   alloc(Nn*4);              // contiguous with S (one memset)
  float*  S      = (float*) alloc((size_t)Nn*Nn*4);
  ushort* Sb     = (ushort*)alloc((size_t)Nn*Nn*2);
  ushort* Mbits  = (ushort*)alloc((size_t)Nn*32*2);
  ushort* Wtq    = (ushort*)alloc((size_t)Dd*Dd*2);
  ushort* Wtk    = (ushort*)alloc((size_t)Dd*Dd*2);
  ushort* Wtv    = (ushort*)alloc((size_t)Dd*Dd*2);
  ushort* Wto    = (ushort*)alloc((size_t)Dd*Dd*2);
  size_t tszb = (size_t)Bc*Nn*Dd*sizeof(ushort);
  ushort* Ttq = (ushort*)alloc(tszb);
  ushort* Ttk = (ushort*)alloc(tszb);
  ushort* Ttv = (ushort*)alloc(tszb);
  ushort* Qh  = (ushort*)alloc(tszb);
  ushort* Kh  = (ushort*)alloc(tszb);
  ushort* Vt  = (ushort*)alloc(tszb);
  ushort* xh  = (ushort*)alloc(tszb);

  hipMemsetAsync(count, 0, Nn*4 + (size_t)Nn*Nn*4, stream);   // count + S, contiguous

  k_count  <<<Ee/256, 256, 0, stream>>>(ei, count);
  k_scatter<<<Ee/256, 256, 0, stream>>>(ei, count, S);
  k_sbf    <<<Nn*Nn/1024, 256, 0, stream>>>(S, count, Sb);

  dim3 gw(4, 4, 5);   // z=0..3: weight transpose; z=4: mask bit-pack
  k_wt<<<gw, 256, 0, stream>>>(Wq, Wk, Wv, Wo, mask, Wtq, Wtk, Wtv, Wto, Mbits);

  dim3 gp(4, 4, 96);
  k_proj<<<gp, 256, 0, stream>>>(query, key, value, Wtq, Wtk, Wtv, Ttq, Ttk, Ttv);
  k_agge<<<gp, 256, 0, stream>>>(Sb, Ttq, Ttk, Ttv, bq, bk, bv, Qh, Kh, Vt);

  k_attn<<<Bc*Hh*8, 256, 0, stream>>>(Qh, Kh, Vt, Mbits, xh);

  dim3 go(Bc*Nn/128, Dd/64);   // (128, 4)
  k_gemm_o<<<go, 256, 0, stream>>>(xh, Wto, bo, (float*)d_out);
}

// Round 8
// 205.773 us; speedup vs baseline: 1.3572x; 1.3572x over previous
//
#include <hip/hip_runtime.h>
#include <hip/hip_bf16.h>
#include <math.h>

// Problem constants
#define Bc  32
#define Nn  512
#define Dd  256
#define Hh  8
#define HDd 32
#define Ee  16384
#define KT  128   // attention k-tile

typedef __attribute__((ext_vector_type(8))) short bf16x8;
typedef __attribute__((ext_vector_type(4))) float f32x4;

__device__ inline ushort f2bf(float x){
  union { float f; unsigned u; } v; v.f = x;
  return (ushort)((v.u + 0x7fff + ((v.u >> 16) & 1)) >> 16);   // RNE
}

// async global->LDS DMA, 16B per lane; LDS dest = wave-uniform base + lane*16
__device__ __forceinline__ void load_lds16(const ushort* g, ushort* l){
  __builtin_amdgcn_global_load_lds((const __attribute__((address_space(1))) unsigned int*)g,
                                   (__attribute__((address_space(3))) unsigned int*)l, 16, 0, 0);
}

// ---------------- graph prep: dense normalized adjacency ----------------

__global__ __launch_bounds__(256) void k_count(const int* __restrict__ ei, int* __restrict__ count){
  int e = blockIdx.x*256 + threadIdx.x;
  if (e < Ee) atomicAdd(&count[ei[Ee + e]], 1);
}

__global__ __launch_bounds__(256) void k_scatter(const int* __restrict__ ei, const int* __restrict__ count,
                                                 float* __restrict__ S){
  int e = blockIdx.x*256 + threadIdx.x;
  if (e < Ee){
    int s = ei[e], d = ei[Ee + e];
    float w = rsqrtf((1.0f + (float)count[s]) * (1.0f + (float)count[d]));
    atomicAdd(&S[d*Nn + s], w);   // duplicates accumulate, matches ref
  }
}

// add self-loop diagonal, convert to bf16
__global__ __launch_bounds__(256) void k_sbf(const float* __restrict__ S, const int* __restrict__ count,
                                             ushort* __restrict__ Sb){
  int base = (blockIdx.x*256 + threadIdx.x)*4;
  #pragma unroll
  for (int j = 0; j < 4; j++){
    int i = base + j;
    int d = i >> 9, s = i & (Nn-1);
    float v = S[i] + ((d == s) ? 1.0f/(1.0f + (float)count[d]) : 0.0f);
    Sb[i] = f2bf(v);
  }
}

// ---------------- X -> bf16 (enables DMA staging in k_proj) ----------------
__global__ __launch_bounds__(256) void k_xbf(const float* __restrict__ q, const float* __restrict__ k,
                                             const float* __restrict__ v, ushort* __restrict__ Xb){
  int bid = blockIdx.x;                 // 6144 blocks; 2048 per input
  int which = bid >> 11;
  const float* src = (which==0)?q:(which==1)?k:v;
  size_t base = ((size_t)(bid & 2047))*2048 + threadIdx.x*8;
  float tmp[8];
  *(float4*)(tmp)   = *(const float4*)(src + base);
  *(float4*)(tmp+4) = *(const float4*)(src + base + 4);
  ushort o[8];
  #pragma unroll
  for (int j = 0; j < 8; j++) o[j] = f2bf(tmp[j]);
  *(int4*)(Xb + (size_t)which*Bc*Nn*Dd + base) = *(int4*)o;
}

// ---------------- W transpose+convert (z<4) + mask bit-pack (z==4) ----------------
__global__ __launch_bounds__(256) void k_wt(const float* __restrict__ Wq, const float* __restrict__ Wk,
                                            const float* __restrict__ Wv, const float* __restrict__ Wo,
                                            const int* __restrict__ mask,
                                            ushort* __restrict__ Wtq, ushort* __restrict__ Wtk,
                                            ushort* __restrict__ Wtv, ushort* __restrict__ Wto,
                                            ushort* __restrict__ Mbits){
  __shared__ float Ls[64][65];
  int mat = blockIdx.z;
  if (mat == 4){
    int bid = blockIdx.y*4 + blockIdx.x;        // 0..15
    int w0 = bid*1024 + threadIdx.x*4;
    #pragma unroll
    for (int j = 0; j < 4; j++){
      int w = w0 + j;
      int row = w >> 5, c0 = (w & 31) << 4;
      unsigned bits = 0;
      #pragma unroll
      for (int i = 0; i < 16; i++)
        bits |= (mask[(size_t)row*Nn + c0 + i] != 0 ? 1u : 0u) << i;
      Mbits[w] = (ushort)bits;
    }
    return;
  }
  const float* Wsrc = (mat==0)?Wq:(mat==1)?Wk:(mat==2)?Wv:Wo;
  ushort* Wt = (mat==0)?Wtq:(mat==1)?Wtk:(mat==2)?Wtv:Wto;
  int k0 = blockIdx.x*64, n0 = blockIdx.y*64;
  int t = threadIdx.x;
  {
    int r = t >> 2, c4 = (t & 3)*16;
    #pragma unroll
    for (int j = 0; j < 16; j += 4)
      *(float4*)&Ls[r][c4+j] = *(const float4*)(Wsrc + (size_t)(k0+r)*Dd + n0 + c4 + j);
  }
  __syncthreads();
  int nr = t >> 2, kc = (t & 3)*16;
  ushort hb[16];
  #pragma unroll
  for (int j = 0; j < 16; j++) hb[j] = f2bf(Ls[kc+j][nr]);
  size_t dst = (size_t)(n0+nr)*Dd + k0 + kc;
  *(int4*)(Wt + dst)     = ((int4*)hb)[0];
  *(int4*)(Wt + dst + 8) = ((int4*)hb)[1];
}

// ============ shared GEMM pieces (128x64 tile, K-chunk 64, DMA staging) ============
// LDS layout: unpadded [row][64] ushorts; chunk slot s of row r holds GLOBAL chunk
// s^(r&7) (swizzle applied on the global offset; DMA's LDS side is linear).
// Frag reads: slot ((kk*4+g)^(r&7)) -> 2-way bank alias = free.

#define STAGE_A128(srcp, ldK)                                          \
  _Pragma("unroll")                                                    \
  for (int call = 0; call < 4; call++){                                \
    int id_ = t + call*256;                                            \
    int row_ = id_ >> 3, c8_ = (id_ & 7) ^ (row_ & 7);                 \
    load_lds16((srcp) + (size_t)row_*(ldK) + c8_*8,                    \
               As + ((size_t)call*256 + wave*64)*8);                   \
  }

#define STAGE_B64(srcp, ldK)                                           \
  _Pragma("unroll")                                                    \
  for (int call = 0; call < 2; call++){                                \
    int id_ = t + call*256;                                            \
    int row_ = id_ >> 3, c8_ = (id_ & 7) ^ (row_ & 7);                 \
    load_lds16((srcp) + (size_t)row_*(ldK) + c8_*8,                    \
               Bs + ((size_t)call*256 + wave*64)*8);                   \
  }

#define GEMM_COMPUTE()                                                           \
  _Pragma("unroll")                                                              \
  for (int kk = 0; kk < 2; kk++){                                                \
    bf16x8 af[2];                                                                \
    _Pragma("unroll")                                                            \
    for (int r2 = 0; r2 < 2; r2++){                                              \
      int ra_ = wave*32 + r2*16 + l16;                                           \
      af[r2] = *(const bf16x8*)(As + ra_*64 + (((kk<<2)+g) ^ (ra_&7))*8);        \
    }                                                                            \
    _Pragma("unroll")                                                            \
    for (int nf = 0; nf < 4; nf++){                                              \
      int rb_ = nf*16 + l16;                                                     \
      bf16x8 bfr = *(const bf16x8*)(Bs + rb_*64 + (((kk<<2)+g) ^ (rb_&7))*8);    \
      _Pragma("unroll")                                                          \
      for (int r2 = 0; r2 < 2; r2++)                                             \
        acc[r2][nf] = __builtin_amdgcn_mfma_f32_16x16x32_bf16(af[r2], bfr, acc[r2][nf], 0, 0, 0); \
    }                                                                            \
  }

// XCD-aware decode for grid=1536 (proj/agge): each XCD owns 12 z-slices complete
#define DECODE_PAZ()                                                   \
  int bid = blockIdx.x;                                                \
  int xcd = bid & 7, j_ = bid >> 3;                                    \
  int z = xcd*12 + (j_ % 12);                                          \
  int rr_ = j_ / 12;                                                   \
  int m0 = (rr_ & 3)*128, n0 = (rr_ >> 2)*64;                          \
  int which = z >> 5, b = z & 31;

// ---------------- k_proj: T = Xb@W (no bias), output transposed Tt[b][ch][node]
__global__ __launch_bounds__(256) void k_proj(const ushort* __restrict__ Xb,
                                              const ushort* __restrict__ Wtq, const ushort* __restrict__ Wtk,
                                              const ushort* __restrict__ Wtv,
                                              ushort* __restrict__ Ttq, ushort* __restrict__ Ttk,
                                              ushort* __restrict__ Ttv){
  __shared__ ushort LB[128*64 + 64*64];   // 24 KB; also aliased as Ts[64][136] in epilogue
  ushort* As = LB;
  ushort* Bs = LB + 128*64;

  DECODE_PAZ();
  const ushort* X  = Xb + (size_t)which*Bc*Nn*Dd;
  const ushort* Wt = (which==0)?Wtq:(which==1)?Wtk:Wtv;
  ushort*       Tt = (which==0)?Ttq:(which==1)?Ttk:Ttv;

  int t = threadIdx.x, wave = t >> 6, lane = t & 63;
  int g = lane >> 4, l16 = lane & 15;

  f32x4 acc[2][4] = {};

  for (int k0 = 0; k0 < Dd; k0 += 64){
    STAGE_A128(X + ((size_t)b*Nn + m0)*Dd + k0, Dd);
    STAGE_B64(Wt + (size_t)n0*Dd + k0, Dd);
    __syncthreads();
    GEMM_COMPUTE();
    __syncthreads();
  }

  // transposed epilogue via LDS: Ts[n_local][m_local], 64 x 128 (stride 136)
  ushort (*Ts)[136] = (ushort (*)[136])(void*)LB;
  #pragma unroll
  for (int nf = 0; nf < 4; nf++)
    #pragma unroll
    for (int r2 = 0; r2 < 2; r2++)
      #pragma unroll
      for (int q4 = 0; q4 < 4; q4++)
        Ts[nf*16 + l16][wave*32 + r2*16 + g*4 + q4] = f2bf(acc[r2][nf][q4]);
  __syncthreads();
  #pragma unroll
  for (int i = 0; i < 4; i++){
    int id = t + i*256;
    int nr = id >> 4, mc = (id & 15)*8;
    *(int4*)(Tt + ((size_t)b*Dd + n0 + nr)*Nn + m0 + mc) = *(int4*)&Ts[nr][mc];
  }
}

// ---------------- k_agge: QKV = S @ T + bias
// Q -> head layout pre-scaled by 1/sqrt(32)*log2(e); K -> head layout; V -> Vt[b][ch][node]
__global__ __launch_bounds__(256) void k_agge(const ushort* __restrict__ Sb,
                                              const ushort* __restrict__ Ttq, const ushort* __restrict__ Ttk,
                                              const ushort* __restrict__ Ttv,
                                              const float* __restrict__ bq, const float* __restrict__ bk,
                                              const float* __restrict__ bv,
                                              ushort* __restrict__ Qh, ushort* __restrict__ Kh,
                                              ushort* __restrict__ Vt){
  __shared__ ushort LB[128*64 + 64*64];
  ushort* As = LB;
  ushort* Bs = LB + 128*64;

  DECODE_PAZ();
  const ushort* Tt  = (which==0)?Ttq:(which==1)?Ttk:Ttv;
  const float*  bia = (which==0)?bq:(which==1)?bk:bv;

  int t = threadIdx.x, wave = t >> 6, lane = t & 63;
  int g = lane >> 4, l16 = lane & 15;

  f32x4 acc[2][4] = {};

  for (int k0 = 0; k0 < Nn; k0 += 64){
    STAGE_A128(Sb + (size_t)m0*Nn + k0, Nn);
    STAGE_B64(Tt + ((size_t)b*Dd + n0)*Nn + k0, Nn);
    __syncthreads();
    GEMM_COMPUTE();
    __syncthreads();
  }

  const float qscale = 0.17677669529663687f * 1.4426950408889634f;  // 1/sqrt(32)*log2(e)

  if (which == 2){
    // V: bias then LDS-transpose -> Vt[(b*256 + channel)][node]
    ushort (*Ts)[136] = (ushort (*)[136])(void*)LB;
    #pragma unroll
    for (int nf = 0; nf < 4; nf++)
      #pragma unroll
      for (int r2 = 0; r2 < 2; r2++)
        #pragma unroll
        for (int q4 = 0; q4 < 4; q4++){
          int n = n0 + nf*16 + l16;
          Ts[nf*16 + l16][wave*32 + r2*16 + g*4 + q4] = f2bf(acc[r2][nf][q4] + bia[n]);
        }
    __syncthreads();
    #pragma unroll
    for (int i = 0; i < 4; i++){
      int id = t + i*256;
      int nr = id >> 4, mc = (id & 15)*8;
      *(int4*)(Vt + ((size_t)b*Dd + n0 + nr)*Nn + m0 + mc) = *(int4*)&Ts[nr][mc];
    }
  } else {
    ushort* out = (which==0) ? Qh : Kh;
    float sc = (which==0) ? qscale : 1.0f;
    #pragma unroll
    for (int nf = 0; nf < 4; nf++){
      #pragma unroll
      for (int r2 = 0; r2 < 2; r2++)
        #pragma unroll
        for (int q4 = 0; q4 < 4; q4++){
          int m = m0 + wave*32 + r2*16 + g*4 + q4;   // node
          int n = n0 + nf*16 + l16;                  // out channel
          float val = (acc[r2][nf][q4] + bia[n]) * sc;
          int h = n >> 5, hd = n & 31;
          out[((size_t)(b*Hh + h)*Nn + m)*HDd + hd] = f2bf(val);
        }
    }
  }
}

// ---------------- MFMA attention (unchanged from R6) ----------------
__global__ __launch_bounds__(256) void k_attn(const ushort* __restrict__ Qg, const ushort* __restrict__ Kg,
                                              const ushort* __restrict__ Vt, const ushort* __restrict__ Mbits,
                                              ushort* __restrict__ xh){
  __shared__ ushort Ks[KT][40];        // K rows [k][hd]
  __shared__ ushort Vs[HDd][KT+8];     // V^T [hd][k]
  __shared__ ushort Ps[4][16][KT+8];   // per-wave P bf16

  int bx = blockIdx.x;
  int bh = bx & 255;
  int qt = bx >> 8;
  int b = bh >> 3, h = bh & 7;
  int t = threadIdx.x, wave = t >> 6, lane = t & 63;
  int g = lane >> 4, l16 = lane & 15;

  const ushort* Qp = Qg + (size_t)bh*Nn*HDd;
  const ushort* Kp = Kg + (size_t)bh*Nn*HDd;
  const ushort* Vp = Vt + (size_t)bh*HDd*Nn;

  int q0 = qt*64 + wave*16;
  bf16x8 qfrag = *(const bf16x8*)(Qp + (size_t)(q0 + l16)*HDd + g*8);

  bf16x8 ones;
  #pragma unroll
  for (int j = 0; j < 8; j++) ones[j] = (short)0x3F80;   // 1.0 bf16

  f32x4 Ofrag[2] = {{0,0,0,0},{0,0,0,0}};
  f32x4 rs = {0,0,0,0};

  for (int kt = 0; kt < Nn; kt += KT){
    #pragma unroll
    for (int i = 0; i < 2; i++){
      int id = t + i*256;
      int r = id >> 2, c = (id & 3)*8;
      *(int4*)&Ks[r][c] = *(const int4*)(Kp + (size_t)(kt + r)*HDd + c);
    }
    #pragma unroll
    for (int i = 0; i < 2; i++){
      int id = t + i*256;
      int r = id >> 4, c = (id & 15)*8;
      *(int4*)&Vs[r][c] = *(const int4*)(Vp + (size_t)r*Nn + kt + c);
    }
    __syncthreads();

    int4 mb4[4];
    #pragma unroll
    for (int r = 0; r < 4; r++)
      mb4[r] = *(const int4*)(Mbits + (size_t)(q0 + g*4 + r)*32 + (kt >> 4));

    #pragma unroll
    for (int f = 0; f < KT/16; f++){
      bf16x8 kfrag = *(const bf16x8*)&Ks[f*16 + l16][g*8];
      f32x4 ci;
      #pragma unroll
      for (int r = 0; r < 4; r++){
        unsigned w = ((const unsigned*)&mb4[r])[f >> 1];
        unsigned bit = (w >> ((f & 1)*16 + l16)) & 1u;
        ci[r] = bit ? 0.0f : -1e30f;
      }
      f32x4 s = __builtin_amdgcn_mfma_f32_16x16x32_bf16(qfrag, kfrag, ci, 0, 0, 0);
      #pragma unroll
      for (int r = 0; r < 4; r++){
        float e = __builtin_exp2f(s[r]);            // masked -> 0
        union { float f; unsigned u; } cv; cv.f = e;
        Ps[wave][g*4 + r][f*16 + l16] = (ushort)((cv.u + 0x8000u) >> 16);
      }
    }
    // no barrier: Ps is wave-private, lgkmcnt orders RAW

    #pragma unroll
    for (int ks = 0; ks < KT/32; ks++){
      bf16x8 af = *(const bf16x8*)&Ps[wave][l16][ks*32 + g*8];
      rs = __builtin_amdgcn_mfma_f32_16x16x32_bf16(af, ones, rs, 0, 0, 0);  // row sums
      #pragma unroll
      for (int nt = 0; nt < 2; nt++){
        bf16x8 vf = *(const bf16x8*)&Vs[nt*16 + l16][ks*32 + g*8];
        Ofrag[nt] = __builtin_amdgcn_mfma_f32_16x16x32_bf16(af, vf, Ofrag[nt], 0, 0, 0);
      }
    }
    __syncthreads();
  }

  float inv[4];
  #pragma unroll
  for (int r = 0; r < 4; r++) inv[r] = 1.0f / rs[r];

  #pragma unroll
  for (int nt = 0; nt < 2; nt++){
    #pragma unroll
    for (int r = 0; r < 4; r++){
      int row = q0 + g*4 + r;
      int col = h*HDd + nt*16 + l16;
      xh[((size_t)b*Nn + row)*Dd + col] = f2bf(Ofrag[nt][r] * inv[r]);
    }
  }
}

// ---------------- out-projection: C = x@Wo + bo, DMA-staged bf16 MFMA
__global__ __launch_bounds__(256) void k_gemm_o(const ushort* __restrict__ xh,
                                                const ushort* __restrict__ Wto,
                                                const float* __restrict__ bo, float* __restrict__ out){
  __shared__ ushort LB[128*64 + 64*64];
  ushort* As = LB;
  ushort* Bs = LB + 128*64;

  // XCD-aware: 512 blocks; each XCD owns 16 consecutive m-tiles complete (y-siblings local)
  int bid = blockIdx.x;
  int xcd = bid & 7, j_ = bid >> 3;            // j_ 0..63
  int m0 = (xcd*16 + (j_ >> 2))*128;
  int n0 = (j_ & 3)*64;

  int t = threadIdx.x, wave = t >> 6, lane = t & 63;
  int g = lane >> 4, l16 = lane & 15;

  f32x4 acc[2][4] = {};

  for (int k0 = 0; k0 < Dd; k0 += 64){
    STAGE_A128(xh + (size_t)m0*Dd + k0, Dd);
    STAGE_B64(Wto + (size_t)n0*Dd + k0, Dd);
    __syncthreads();
    GEMM_COMPUTE();
    __syncthreads();
  }

  #pragma unroll
  for (int nf = 0; nf < 4; nf++){
    #pragma unroll
    for (int r2 = 0; r2 < 2; r2++)
      #pragma unroll
      for (int q4 = 0; q4 < 4; q4++){
        int m = m0 + wave*32 + r2*16 + g*4 + q4;
        int n = n0 + nf*16 + l16;
        out[(size_t)m*Dd + n] = acc[r2][nf][q4] + bo[n];
      }
  }
}

// ---------------- launch ----------------
extern "C" void kernel_launch(void* const* d_in, const int* in_sizes, int n_in,
                              void* d_out, int out_size, void* d_ws, size_t ws_size,
                              hipStream_t stream){
  const float* query = (const float*)d_in[0];
  const float* key   = (const float*)d_in[1];
  const float* value = (const float*)d_in[2];
  const int*   ei    = (const int*)  d_in[3];
  const int*   mask  = (const int*)  d_in[4];
  const float* Wq = (const float*)d_in[5];
  const float* bq = (const float*)d_in[6];
  const float* Wk = (const float*)d_in[7];
  const float* bk = (const float*)d_in[8];
  const float* Wv = (const float*)d_in[9];
  const float* bv = (const float*)d_in[10];
  const float* Wo = (const float*)d_in[11];
  const float* bo = (const float*)d_in[12];

  char* ws = (char*)d_ws;
  size_t off = 0;
  auto alloc = [&](size_t bytes)->void*{
    void* p = ws + off;
    off = (off + bytes + 255) & ~(size_t)255;
    return p;
  };
  int*    count  = (int*)   alloc(Nn*4);              // contiguous with S (one memset)
  float*  S      = (float*) alloc((size_t)Nn*Nn*4);
  ushort* Sb     = (ushort*)alloc((size_t)Nn*Nn*2);
  ushort* Mbits  = (ushort*)alloc((size_t)Nn*32*2);
  ushort* Wtq    = (ushort*)alloc((size_t)Dd*Dd*2);
  ushort* Wtk    = (ushort*)alloc((size_t)Dd*Dd*2);
  ushort* Wtv    = (ushort*)alloc((size_t)Dd*Dd*2);
  ushort* Wto    = (ushort*)alloc((size_t)Dd*Dd*2);
  size_t tszb = (size_t)Bc*Nn*Dd*sizeof(ushort);
  ushort* Xb  = (ushort*)alloc(3*tszb);
  ushort* Ttq = (ushort*)alloc(tszb);
  ushort* Ttk = (ushort*)alloc(tszb);
  ushort* Ttv = (ushort*)alloc(tszb);
  ushort* Qh  = (ushort*)alloc(tszb);
  ushort* Kh  = (ushort*)alloc(tszb);
  ushort* Vt  = (ushort*)alloc(tszb);
  ushort* xh  = (ushort*)alloc(tszb);

  hipMemsetAsync(count, 0, Nn*4 + (size_t)Nn*Nn*4, stream);   // count + S, contiguous

  k_count  <<<Ee/256, 256, 0, stream>>>(ei, count);
  k_scatter<<<Ee/256, 256, 0, stream>>>(ei, count, S);
  k_sbf    <<<Nn*Nn/1024, 256, 0, stream>>>(S, count, Sb);
  k_xbf    <<<6144, 256, 0, stream>>>(query, key, value, Xb);

  dim3 gw(4, 4, 5);   // z=0..3: weight transpose; z=4: mask bit-pack
  k_wt<<<gw, 256, 0, stream>>>(Wq, Wk, Wv, Wo, mask, Wtq, Wtk, Wtv, Wto, Mbits);

  k_proj<<<1536, 256, 0, stream>>>(Xb, Wtq, Wtk, Wtv, Ttq, Ttk, Ttv);
  k_agge<<<1536, 256, 0, stream>>>(Sb, Ttq, Ttk, Ttv, bq, bk, bv, Qh, Kh, Vt);

  k_attn<<<Bc*Hh*8, 256, 0, stream>>>(Qh, Kh, Vt, Mbits, xh);

  k_gemm_o<<<512, 256, 0, stream>>>(xh, Wto, bo, (float*)d_out);
}